// Round 6
// baseline (786.958 us; speedup 1.0000x reference)
//
#include <hip/hip_runtime.h>
#include <math.h>

#define B_ 4
#define L_ 1024
#define DM 256
#define DIN 512
#define NST 16
#define DTR 16
#define CHK 32          // number of chunks over L
#define CT (L_ / CHK)   // chunk length = 32

typedef short short8 __attribute__((ext_vector_type(8)));
typedef float float4v __attribute__((ext_vector_type(4)));

__device__ __forceinline__ float softplusf(float x) {
    return (x > 20.f) ? x : log1pf(__expf(x));
}
__device__ __forceinline__ float siluf(float x) {
    return x / (1.f + __expf(-x));
}
__device__ __forceinline__ unsigned short f2bf(float f) {  // RNE bf16
    unsigned int u = __float_as_uint(f);
    u = (u + 0x7fffu + ((u >> 16) & 1u)) >> 16;
    return (unsigned short)u;
}

// two-value block reduction (sum) over 256 threads = 4 waves
__device__ __forceinline__ void block_reduce2(float& a, float& q) {
    #pragma unroll
    for (int off = 32; off > 0; off >>= 1) {
        a += __shfl_down(a, off);
        q += __shfl_down(q, off);
    }
    __shared__ float sa[4], sq[4];
    int lane = threadIdx.x & 63, w = threadIdx.x >> 6;
    if (lane == 0) { sa[w] = a; sq[w] = q; }
    __syncthreads();
    a = sa[0] + sa[1] + sa[2] + sa[3];
    q = sq[0] + sq[1] + sq[2] + sq[3];
}

// ---- fp32 -> bf16 weight conversion, all three weights in one dispatch ----
__global__ __launch_bounds__(256) void f2bf3_kernel(
    const float* __restrict__ a, int na, const float* __restrict__ b, int nb,
    const float* __restrict__ c, int nc,
    unsigned short* __restrict__ oa, unsigned short* __restrict__ ob,
    unsigned short* __restrict__ oc)
{
    int i = blockIdx.x * 256 + threadIdx.x;
    if (i < na) { oa[i] = f2bf(a[i]); return; }
    int j = i - na;
    if (j < nb) { ob[j] = f2bf(b[j]); return; }
    int k = j - nb;
    if (k < nc) oc[k] = f2bf(c[k]);
}

// ---- input projection: h0[b,l,d] = bias[d] + sum_c x[b,c,l] * W[d,c] ----
__global__ __launch_bounds__(256) void input_proj_kernel(
    const float* __restrict__ x, const float* __restrict__ W,
    const float* __restrict__ bias, float* __restrict__ h0)
{
    int idx = blockIdx.x * 256 + threadIdx.x;     // B*L*DM, d fastest
    int d = idx & (DM - 1);
    int bl = idx >> 8;
    int l = bl & (L_ - 1);
    int b = bl >> 10;
    const float* xb = x + (size_t)b * 3 * L_;
    float acc = bias[d];
    acc = fmaf(xb[0 * L_ + l], W[d * 3 + 0], acc);
    acc = fmaf(xb[1 * L_ + l], W[d * 3 + 1], acc);
    acc = fmaf(xb[2 * L_ + l], W[d * 3 + 2], acc);
    h0[idx] = acc;
}

// ---- fused LN + in_proj GEMM: C[M,N] = LN(A)[M,256] @ W[N,256]^T ----
// Block = 64x64 output tile. Phase 1: LN the block's 64 rows (4 thr/row)
// into a full-K bf16 LDS tile. Phase 2: stream W K-slices, MFMA.
// LN is recomputed by each of the 16 n-tiles (cheap, L2-served).
__global__ __launch_bounds__(256) void gemm_in_ln(
    const float* __restrict__ A, const unsigned short* __restrict__ W,
    const float* __restrict__ lw, const float* __restrict__ lb,
    float* __restrict__ C, int N)
{
    __shared__ unsigned short As[64][264];   // 64 rows x K=256 (+8 pad)
    __shared__ unsigned short Ws[64][72];
    const int tid = threadIdx.x;
    const int wave = tid >> 6;
    const int lane = tid & 63;
    const int m_l = lane & 15;
    const int q = lane >> 4;
    const int m0 = blockIdx.y * 64;
    const int n0 = blockIdx.x * 64;

    // ---- phase 1: layernorm rows m0..m0+63 into As ----
    {
        const int r = tid >> 2;               // 0..63
        const int c0 = (tid & 3) * 64;        // 4 threads per row
        const float* ap = A + (size_t)(m0 + r) * DM + c0;
        float4 v[16];
        float s = 0.f, qq = 0.f;
        #pragma unroll
        for (int i = 0; i < 16; ++i) {
            v[i] = *(const float4*)(ap + i * 4);
            s  += v[i].x + v[i].y + v[i].z + v[i].w;
            qq += v[i].x * v[i].x + v[i].y * v[i].y
                + v[i].z * v[i].z + v[i].w * v[i].w;
        }
        s += __shfl_xor(s, 1); qq += __shfl_xor(qq, 1);
        s += __shfl_xor(s, 2); qq += __shfl_xor(qq, 2);
        float mu = s * (1.f / DM);
        float var = qq * (1.f / DM) - mu * mu;
        float rs = rsqrtf(var + 1e-5f);
        #pragma unroll
        for (int i = 0; i < 16; ++i) {
            float4 wv = *(const float4*)(lw + c0 + i * 4);
            float4 bv = *(const float4*)(lb + c0 + i * 4);
            unsigned short* dst = &As[r][c0 + i * 4];
            dst[0] = f2bf((v[i].x - mu) * rs * wv.x + bv.x);
            dst[1] = f2bf((v[i].y - mu) * rs * wv.y + bv.y);
            dst[2] = f2bf((v[i].z - mu) * rs * wv.z + bv.z);
            dst[3] = f2bf((v[i].w - mu) * rs * wv.w + bv.w);
        }
    }
    __syncthreads();

    // ---- phase 2: K-loop, stage W slices, MFMA ----
    const int sr = tid >> 3;          // 0..31 staging row
    const int sc = (tid & 7) * 8;     // staging col (shorts)
    float4v acc[4];
    #pragma unroll
    for (int j = 0; j < 4; ++j) acc[j] = (float4v)(0.f);

    for (int k0 = 0; k0 < DM; k0 += 64) {
        *(short8*)&Ws[sr][sc]      = *(const short8*)(W + (size_t)(n0 + sr) * DM + k0 + sc);
        *(short8*)&Ws[sr + 32][sc] = *(const short8*)(W + (size_t)(n0 + sr + 32) * DM + k0 + sc);
        __syncthreads();
        #pragma unroll
        for (int kk = 0; kk < 64; kk += 32) {
            short8 a = *(const short8*)&As[wave * 16 + m_l][k0 + kk + q * 8];
            #pragma unroll
            for (int j4 = 0; j4 < 4; ++j4) {
                short8 b = *(const short8*)&Ws[j4 * 16 + m_l][kk + q * 8];
                acc[j4] = __builtin_amdgcn_mfma_f32_16x16x32_bf16(a, b, acc[j4], 0, 0, 0);
            }
        }
        __syncthreads();
    }
    #pragma unroll
    for (int j4 = 0; j4 < 4; ++j4) {
        int n = n0 + j4 * 16 + m_l;
        #pragma unroll
        for (int reg = 0; reg < 4; ++reg) {
            int m = m0 + wave * 16 + q * 4 + reg;
            C[(size_t)m * N + n] = acc[j4][reg];
        }
    }
}

// ---- fused conv+silu + x_proj GEMM ----
// dbc[M,48] = xc[M,512] @ xpw[48,512]^T where xc = silu(causalconv(xz_lo)).
// Block = 64 rows (one m-tile, grid.y=64, same b). Per K-slice of 64
// channels: compute conv+silu into LDS A-tile (and write xc fp32 to global
// for the scan), stage W rows, MFMA. N=48 -> 3 j4 tiles.
__global__ __launch_bounds__(256) void conv_xproj(
    const float* __restrict__ xz, const float* __restrict__ cw,
    const float* __restrict__ cb, const unsigned short* __restrict__ W,
    float* __restrict__ xc, float* __restrict__ dbc)
{
    __shared__ unsigned short As[64][72];
    __shared__ unsigned short Ws[48][72];
    const int tid = threadIdx.x;
    const int wave = tid >> 6;
    const int lane = tid & 63;
    const int m_l = lane & 15;
    const int q = lane >> 4;
    const int m0 = blockIdx.y * 64;
    const int b = m0 >> 10;                    // rows never cross batch
    const int l0 = m0 & (L_ - 1);
    const int sr = tid >> 3;
    const int sc = (tid & 7) * 8;

    float4v acc[3];
    #pragma unroll
    for (int j = 0; j < 3; ++j) acc[j] = (float4v)(0.f);

    const int dd = tid & 63;                   // channel within slice
    const int r4 = tid >> 6;                   // row offset 0..3

    for (int k0 = 0; k0 < DIN; k0 += 64) {
        int d = k0 + dd;
        float4 cwv = *(const float4*)(cw + d * 4);
        float cbv = cb[d];
        #pragma unroll 4
        for (int rr = 0; rr < 16; ++rr) {
            int row = rr * 4 + r4;             // 0..63
            int l = l0 + row;
            float a = cbv;
            #pragma unroll
            for (int k = 0; k < 4; ++k) {
                int ls = l - 3 + k;
                if (ls >= 0)
                    a = fmaf(xz[((size_t)((b << 10) + ls)) * (2 * DIN) + d],
                             ((const float*)&cwv)[k], a);
            }
            float v = siluf(a);
            xc[(size_t)(m0 + row) * DIN + d] = v;
            As[row][dd] = f2bf(v);
        }
        // stage W rows 0..47 for this K-slice (sr covers 0..31; second store
        // covers 32..47 — BUG FIX: rows 32..47 were previously never staged)
        *(short8*)&Ws[sr][sc] = *(const short8*)(W + (size_t)sr * DIN + k0 + sc);
        if (sr < 16)
            *(short8*)&Ws[32 + sr][sc] =
                *(const short8*)(W + (size_t)(32 + sr) * DIN + k0 + sc);
        __syncthreads();
        #pragma unroll
        for (int kk = 0; kk < 64; kk += 32) {
            short8 a = *(const short8*)&As[wave * 16 + m_l][kk + q * 8];
            #pragma unroll
            for (int j4 = 0; j4 < 3; ++j4) {
                short8 bf = *(const short8*)&Ws[j4 * 16 + m_l][kk + q * 8];
                acc[j4] = __builtin_amdgcn_mfma_f32_16x16x32_bf16(a, bf, acc[j4], 0, 0, 0);
            }
        }
        __syncthreads();
    }
    #pragma unroll
    for (int j4 = 0; j4 < 3; ++j4) {
        int n = j4 * 16 + m_l;
        #pragma unroll
        for (int reg = 0; reg < 4; ++reg) {
            int m = m0 + wave * 16 + q * 4 + reg;
            dbc[(size_t)m * 48 + n] = acc[j4][reg];
        }
    }
}

// ---- generic bf16 MFMA GEMM (used for out_proj): C (+)= A @ W^T ----
__global__ __launch_bounds__(256) void gemm_bt_bf16(
    const unsigned short* __restrict__ A, const unsigned short* __restrict__ W,
    float* C, int M, int N, int K, int lda, int accumulate)
{
    __shared__ unsigned short As[64][72];
    __shared__ unsigned short Ws[64][72];
    const int tid = threadIdx.x;
    const int wave = tid >> 6;
    const int lane = tid & 63;
    const int m_l = lane & 15;
    const int q = lane >> 4;
    const int m0 = blockIdx.y * 64;
    const int n0 = blockIdx.x * 64;
    const int sr = tid >> 3;
    const int sc = (tid & 7) * 8;

    float4v acc[4];
    #pragma unroll
    for (int j = 0; j < 4; ++j) acc[j] = (float4v)(0.f);

    for (int k0 = 0; k0 < K; k0 += 64) {
        *(short8*)&As[sr][sc]      = *(const short8*)(A + (size_t)(m0 + sr) * lda + k0 + sc);
        *(short8*)&As[sr + 32][sc] = *(const short8*)(A + (size_t)(m0 + sr + 32) * lda + k0 + sc);
        short8 wz = (short8)0;
        int wn0 = n0 + sr, wn1 = n0 + sr + 32;
        *(short8*)&Ws[sr][sc]      = (wn0 < N) ? *(const short8*)(W + (size_t)wn0 * K + k0 + sc) : wz;
        *(short8*)&Ws[sr + 32][sc] = (wn1 < N) ? *(const short8*)(W + (size_t)wn1 * K + k0 + sc) : wz;
        __syncthreads();
        #pragma unroll
        for (int kk = 0; kk < 64; kk += 32) {
            short8 a = *(const short8*)&As[wave * 16 + m_l][kk + q * 8];
            #pragma unroll
            for (int j4 = 0; j4 < 4; ++j4) {
                short8 bf = *(const short8*)&Ws[j4 * 16 + m_l][kk + q * 8];
                acc[j4] = __builtin_amdgcn_mfma_f32_16x16x32_bf16(a, bf, acc[j4], 0, 0, 0);
            }
        }
        __syncthreads();
    }
    #pragma unroll
    for (int j4 = 0; j4 < 4; ++j4) {
        int n = n0 + j4 * 16 + m_l;
        if (n < N) {
            #pragma unroll
            for (int reg = 0; reg < 4; ++reg) {
                int m = m0 + wave * 16 + q * 4 + reg;
                float* cp = C + (size_t)m * N + n;
                if (accumulate) *cp += acc[j4][reg];
                else            *cp  = acc[j4][reg];
            }
        }
    }
}

// ==== chunked selective scan, thread-per-channel, fused delta recompute ====
__global__ __launch_bounds__(256) void scan_summary_kernel(
    const float* __restrict__ dbc, const float* __restrict__ xc,
    const float* __restrict__ A_log, const float* __restrict__ dt_w,
    const float* __restrict__ dt_b,
    float* __restrict__ S, float* __restrict__ H)
{
    const int d = blockIdx.x * 256 + threadIdx.x;
    const int c = blockIdx.y;
    const int b = blockIdx.z;
    float A[NST], tw[DTR];
    #pragma unroll
    for (int j = 0; j < NST; ++j) A[j] = -__expf(A_log[d * NST + j]);
    #pragma unroll
    for (int r = 0; r < DTR; ++r) tw[r] = dt_w[d * DTR + r];
    const float tb = dt_b[d];
    const int l0 = c * CT;
    const float* xp = xc  + ((size_t)(b * L_ + l0)) * DIN + d;
    const float* bc = dbc + ((size_t)(b * L_ + l0)) * 48;
    float h[NST];
    #pragma unroll
    for (int j = 0; j < NST; ++j) h[j] = 0.f;
    float ssum = 0.f;
    #pragma unroll 4
    for (int t = 0; t < CT; ++t) {
        const float* br = bc + t * 48;        // block-uniform row
        float acc = tb;
        #pragma unroll
        for (int r = 0; r < DTR; ++r) acc = fmaf(br[r], tw[r], acc);
        float dlt = softplusf(acc);
        float xcv = xp[t * DIN];
        float t0 = dlt * xcv;
        ssum += dlt;
        #pragma unroll
        for (int j = 0; j < NST; ++j) {
            float dA = __expf(A[j] * dlt);
            h[j] = fmaf(dA, h[j], t0 * br[DTR + j]);
        }
    }
    S[((size_t)b * CHK + c) * DIN + d] = ssum;
    float* Hp = H + (((size_t)b * CHK + c) * DIN + d) * NST;
    #pragma unroll
    for (int j = 0; j < NST; j += 4)
        *(float4*)(Hp + j) = make_float4(h[j], h[j + 1], h[j + 2], h[j + 3]);
}

// apply with fused prefix: prologue reconstructs h_in(c) from raw chunk
// summaries (S = per-chunk sum(delta), H = per-chunk local scan from 0).
__global__ __launch_bounds__(256) void scan_apply_kernel(
    const float* __restrict__ dbc, const float* __restrict__ xc,
    const float* __restrict__ xz, const float* __restrict__ A_log,
    const float* __restrict__ dt_w, const float* __restrict__ dt_b,
    const float* __restrict__ Dskip, const float* __restrict__ S,
    const float* __restrict__ H, unsigned short* __restrict__ y)
{
    const int d = blockIdx.x * 256 + threadIdx.x;
    const int c = blockIdx.y;
    const int b = blockIdx.z;
    float A[NST], tw[DTR];
    #pragma unroll
    for (int j = 0; j < NST; ++j) A[j] = -__expf(A_log[d * NST + j]);
    #pragma unroll
    for (int r = 0; r < DTR; ++r) tw[r] = dt_w[d * DTR + r];
    const float tb = dt_b[d];
    const float Dsk = Dskip[d];
    const int l0 = c * CT;
    const float* xp = xc  + ((size_t)(b * L_ + l0)) * DIN + d;
    const float* bc = dbc + ((size_t)(b * L_ + l0)) * 48;
    const float* zp = xz  + ((size_t)(b * L_ + l0)) * (2 * DIN) + DIN + d;
    unsigned short* yp = y + ((size_t)(b * L_ + l0)) * DIN + d;

    // prologue: h_in(c) = scan over chunk summaries 0..c-1
    float h[NST];
    #pragma unroll
    for (int j = 0; j < NST; ++j) h[j] = 0.f;
    {
        const float* Sp = S + (size_t)b * CHK * DIN + d;
        const float* Hp = H + ((size_t)b * CHK * DIN + d) * NST;
        for (int cc = 0; cc < c; ++cc) {
            float Sc = Sp[(size_t)cc * DIN];
            const float* Hc = Hp + (size_t)cc * DIN * NST;
            #pragma unroll
            for (int j = 0; j < NST; ++j)
                h[j] = fmaf(__expf(A[j] * Sc), h[j], Hc[j]);
        }
    }

    #pragma unroll 4
    for (int t = 0; t < CT; ++t) {
        const float* br = bc + t * 48;        // block-uniform row
        float acc = tb;
        #pragma unroll
        for (int r = 0; r < DTR; ++r) acc = fmaf(br[r], tw[r], acc);
        float dlt = softplusf(acc);
        float xcv = xp[t * DIN];
        float zv  = zp[t * (2 * DIN)];
        float t0 = dlt * xcv;
        float p = 0.f;
        #pragma unroll
        for (int j = 0; j < NST; ++j) {
            float dA = __expf(A[j] * dlt);
            h[j] = fmaf(dA, h[j], t0 * br[DTR + j]);
            p = fmaf(h[j], br[DTR + NST + j], p);
        }
        yp[t * DIN] = f2bf((p + xcv * Dsk) * siluf(zv));
    }
}

// ---- mean over L -> layernorm -> classifier; one block per batch ----
__global__ __launch_bounds__(256) void head_kernel(
    const float* __restrict__ h, const float* __restrict__ fn_w,
    const float* __restrict__ fn_b, const float* __restrict__ cls_w,
    const float* __restrict__ cls_b, float* __restrict__ out)
{
    int b = blockIdx.x, t = threadIdx.x;
    const float* hp = h + (size_t)b * L_ * DM + t;
    float s = 0.f;
    for (int l = 0; l < L_; ++l) s += hp[(size_t)l * DM];
    s *= (1.f / L_);
    float a = s, q = s * s;
    block_reduce2(a, q);
    float mu = a * (1.f / DM);
    float var = q * (1.f / DM) - mu * mu;
    float v = (s - mu) * rsqrtf(var + 1e-5f) * fn_w[t] + fn_b[t];
    __shared__ float pooled[DM];
    pooled[t] = v;
    __syncthreads();
    if (t < 10) {
        float acc = cls_b[t];
        for (int d2 = 0; d2 < DM; ++d2)
            acc = fmaf(pooled[d2], cls_w[t * DM + d2], acc);
        out[b * 10 + t] = acc;
    }
}

extern "C" void kernel_launch(void* const* d_in, const int* in_sizes, int n_in,
                              void* d_out, int out_size, void* d_ws, size_t ws_size,
                              hipStream_t stream)
{
    const float* x    = (const float*)d_in[0];
    const float* ipw  = (const float*)d_in[1];
    const float* ipb  = (const float*)d_in[2];
    const float* inw  = (const float*)d_in[3];
    const float* cw   = (const float*)d_in[4];
    const float* cb   = (const float*)d_in[5];
    const float* xpw  = (const float*)d_in[6];
    const float* dtw  = (const float*)d_in[7];
    const float* dtb  = (const float*)d_in[8];
    const float* alog = (const float*)d_in[9];
    const float* dsk  = (const float*)d_in[10];
    const float* opw  = (const float*)d_in[11];
    const float* lnw  = (const float*)d_in[12];
    const float* lnb  = (const float*)d_in[13];
    const float* fnw  = (const float*)d_in[14];
    const float* fnb  = (const float*)d_in[15];
    const float* clw  = (const float*)d_in[16];
    const float* clb  = (const float*)d_in[17];

    // workspace layout (float units)
    float* ws     = (float*)d_ws;
    float* hbuf   = ws;                                   // B*L*DM = 1,048,576 f
    float* xzbuf  = hbuf   + (size_t)B_ * L_ * DM;        // 4,194,304 f
    float* xcbuf  = xzbuf  + (size_t)B_ * L_ * 2 * DIN;   // 2,097,152 f
    float* dbcbuf = xcbuf  + (size_t)B_ * L_ * DIN;       //   196,608 f
    float* Sbuf   = dbcbuf + (size_t)B_ * L_ * 48;        //    65,536 f
    float* Hbuf   = Sbuf   + (size_t)B_ * CHK * DIN;      // 1,048,576 f
    float* tail   = Hbuf   + (size_t)B_ * CHK * DIN * NST;
    unsigned short* yb16  = (unsigned short*)tail;                  // B*L*DIN sh
    unsigned short* inw16 = yb16  + (size_t)B_ * L_ * DIN;// 4*1024*256
    unsigned short* xpw16 = inw16 + (size_t)4 * 1024 * DM;// 4*48*512
    unsigned short* opw16 = xpw16 + (size_t)4 * 48 * DIN; // 4*256*512

    const int BL = B_ * L_;                               // 4096
    const int NIN = 4 * 1024 * DM, NXP = 4 * 48 * DIN, NOP = 4 * DM * DIN;

    f2bf3_kernel<<<(NIN + NXP + NOP + 255) / 256, 256, 0, stream>>>(
        inw, NIN, xpw, NXP, opw, NOP, inw16, xpw16, opw16);

    input_proj_kernel<<<BL * DM / 256, 256, 0, stream>>>(x, ipw, ipb, hbuf);

    for (int i = 0; i < 4; ++i) {
        // xz = LN(h) @ in_w^T   [4096,1024], LN fused
        gemm_in_ln<<<dim3(2 * DIN / 64, BL / 64), 256, 0, stream>>>(
            hbuf, inw16 + (size_t)i * 1024 * DM, lnw + i * DM, lnb + i * DM,
            xzbuf, 2 * DIN);
        // xc = silu(conv(xz_lo)); dbc = xc @ xp_w^T   (fused)
        conv_xproj<<<dim3(1, BL / 64), 256, 0, stream>>>(
            xzbuf, cw + i * DIN * 4, cb + i * DIN,
            xpw16 + (size_t)i * 48 * DIN, xcbuf, dbcbuf);
        // chunked scan: summary -> apply (prefix fused into apply)
        scan_summary_kernel<<<dim3(DIN / 256, CHK, B_), 256, 0, stream>>>(
            dbcbuf, xcbuf, alog + i * DIN * NST, dtw + i * DIN * DTR,
            dtb + i * DIN, Sbuf, Hbuf);
        scan_apply_kernel<<<dim3(DIN / 256, CHK, B_), 256, 0, stream>>>(
            dbcbuf, xcbuf, xzbuf, alog + i * DIN * NST, dtw + i * DIN * DTR,
            dtb + i * DIN, dsk + i * DIN, Sbuf, Hbuf, yb16);
        // h += y @ out_w^T   [4096,256]
        gemm_bt_bf16<<<dim3(DM / 64, BL / 64), 256, 0, stream>>>(
            yb16, opw16 + (size_t)i * DM * DIN, hbuf, BL, DM, DIN, DIN, 1);
    }

    head_kernel<<<B_, 256, 0, stream>>>(hbuf, fnw, fnb, clw, clb, (float*)d_out);
}

// Round 7
// 625.937 us; speedup vs baseline: 1.2572x; 1.2572x over previous
//
#include <hip/hip_runtime.h>
#include <math.h>

#define B_ 4
#define L_ 1024
#define DM 256
#define DIN 512
#define NST 16
#define DTR 16
#define CHK 32          // number of chunks over L
#define CT (L_ / CHK)   // chunk length = 32

typedef short short8 __attribute__((ext_vector_type(8)));
typedef float float4v __attribute__((ext_vector_type(4)));

__device__ __forceinline__ float softplusf(float x) {
    return (x > 20.f) ? x : log1pf(__expf(x));
}
__device__ __forceinline__ float siluf(float x) {
    return x / (1.f + __expf(-x));
}
__device__ __forceinline__ unsigned short f2bf(float f) {  // RNE bf16
    unsigned int u = __float_as_uint(f);
    u = (u + 0x7fffu + ((u >> 16) & 1u)) >> 16;
    return (unsigned short)u;
}

// two-value block reduction (sum) over 256 threads = 4 waves
__device__ __forceinline__ void block_reduce2(float& a, float& q) {
    #pragma unroll
    for (int off = 32; off > 0; off >>= 1) {
        a += __shfl_down(a, off);
        q += __shfl_down(q, off);
    }
    __shared__ float sa[4], sq[4];
    int lane = threadIdx.x & 63, w = threadIdx.x >> 6;
    if (lane == 0) { sa[w] = a; sq[w] = q; }
    __syncthreads();
    a = sa[0] + sa[1] + sa[2] + sa[3];
    q = sq[0] + sq[1] + sq[2] + sq[3];
}

// ---- fp32 -> bf16 weight conversion, all three weights in one dispatch ----
__global__ __launch_bounds__(256) void f2bf3_kernel(
    const float* __restrict__ a, int na, const float* __restrict__ b, int nb,
    const float* __restrict__ c, int nc,
    unsigned short* __restrict__ oa, unsigned short* __restrict__ ob,
    unsigned short* __restrict__ oc)
{
    int i = blockIdx.x * 256 + threadIdx.x;
    if (i < na) { oa[i] = f2bf(a[i]); return; }
    int j = i - na;
    if (j < nb) { ob[j] = f2bf(b[j]); return; }
    int k = j - nb;
    if (k < nc) oc[k] = f2bf(c[k]);
}

// ---- input projection: h0[b,l,d] = bias[d] + sum_c x[b,c,l] * W[d,c] ----
__global__ __launch_bounds__(256) void input_proj_kernel(
    const float* __restrict__ x, const float* __restrict__ W,
    const float* __restrict__ bias, float* __restrict__ h0)
{
    int idx = blockIdx.x * 256 + threadIdx.x;     // B*L*DM, d fastest
    int d = idx & (DM - 1);
    int bl = idx >> 8;
    int l = bl & (L_ - 1);
    int b = bl >> 10;
    const float* xb = x + (size_t)b * 3 * L_;
    float acc = bias[d];
    acc = fmaf(xb[0 * L_ + l], W[d * 3 + 0], acc);
    acc = fmaf(xb[1 * L_ + l], W[d * 3 + 1], acc);
    acc = fmaf(xb[2 * L_ + l], W[d * 3 + 2], acc);
    h0[idx] = acc;
}

// ---- fused LN + in_proj GEMM: C[M,N] = LN(A)[M,256] @ W[N,256]^T ----
// Phase 1 (v2, coalesced + low-VGPR): 4 passes; per pass each wave handles
// 4 rows with 16 lanes/row -> 256B contiguous loads, 16 live floats/thread,
// 16-lane shuffle reduce. Phase 2: stream W K-slices, MFMA.
__global__ __launch_bounds__(256) void gemm_in_ln(
    const float* __restrict__ A, const unsigned short* __restrict__ W,
    const float* __restrict__ lw, const float* __restrict__ lb,
    float* __restrict__ C, int N)
{
    __shared__ unsigned short As[64][264];   // 64 rows x K=256 (+8 pad)
    __shared__ unsigned short Ws[64][72];
    const int tid = threadIdx.x;
    const int wave = tid >> 6;
    const int lane = tid & 63;
    const int m_l = lane & 15;
    const int q = lane >> 4;
    const int m0 = blockIdx.y * 64;
    const int n0 = blockIdx.x * 64;

    // ---- phase 1: layernorm rows m0..m0+63 into As (bf16) ----
    {
        const int rg = lane >> 4;          // row within wave's group of 4
        const int c4 = lane & 15;          // col quad index
        #pragma unroll
        for (int p = 0; p < 4; ++p) {
            int r = p * 16 + wave * 4 + rg;        // 0..63
            const float* ap = A + (size_t)(m0 + r) * DM;
            float4 v[4];
            float s = 0.f, qq = 0.f;
            #pragma unroll
            for (int i = 0; i < 4; ++i) {
                v[i] = *(const float4*)(ap + i * 64 + c4 * 4);
                s  += v[i].x + v[i].y + v[i].z + v[i].w;
                qq += v[i].x * v[i].x + v[i].y * v[i].y
                    + v[i].z * v[i].z + v[i].w * v[i].w;
            }
            s += __shfl_xor(s, 1); qq += __shfl_xor(qq, 1);
            s += __shfl_xor(s, 2); qq += __shfl_xor(qq, 2);
            s += __shfl_xor(s, 4); qq += __shfl_xor(qq, 4);
            s += __shfl_xor(s, 8); qq += __shfl_xor(qq, 8);
            float mu = s * (1.f / DM);
            float var = qq * (1.f / DM) - mu * mu;
            float rs = rsqrtf(var + 1e-5f);
            #pragma unroll
            for (int i = 0; i < 4; ++i) {
                int col = i * 64 + c4 * 4;
                float4 wv = *(const float4*)(lw + col);
                float4 bv = *(const float4*)(lb + col);
                unsigned short* dst = &As[r][col];
                dst[0] = f2bf((v[i].x - mu) * rs * wv.x + bv.x);
                dst[1] = f2bf((v[i].y - mu) * rs * wv.y + bv.y);
                dst[2] = f2bf((v[i].z - mu) * rs * wv.z + bv.z);
                dst[3] = f2bf((v[i].w - mu) * rs * wv.w + bv.w);
            }
        }
    }
    __syncthreads();

    // ---- phase 2: K-loop, stage W slices, MFMA ----
    const int sr = tid >> 3;          // 0..31 staging row
    const int sc = (tid & 7) * 8;     // staging col (shorts)
    float4v acc[4];
    #pragma unroll
    for (int j = 0; j < 4; ++j) acc[j] = (float4v)(0.f);

    for (int k0 = 0; k0 < DM; k0 += 64) {
        *(short8*)&Ws[sr][sc]      = *(const short8*)(W + (size_t)(n0 + sr) * DM + k0 + sc);
        *(short8*)&Ws[sr + 32][sc] = *(const short8*)(W + (size_t)(n0 + sr + 32) * DM + k0 + sc);
        __syncthreads();
        #pragma unroll
        for (int kk = 0; kk < 64; kk += 32) {
            short8 a = *(const short8*)&As[wave * 16 + m_l][k0 + kk + q * 8];
            #pragma unroll
            for (int j4 = 0; j4 < 4; ++j4) {
                short8 b = *(const short8*)&Ws[j4 * 16 + m_l][kk + q * 8];
                acc[j4] = __builtin_amdgcn_mfma_f32_16x16x32_bf16(a, b, acc[j4], 0, 0, 0);
            }
        }
        __syncthreads();
    }
    #pragma unroll
    for (int j4 = 0; j4 < 4; ++j4) {
        int n = n0 + j4 * 16 + m_l;
        #pragma unroll
        for (int reg = 0; reg < 4; ++reg) {
            int m = m0 + wave * 16 + q * 4 + reg;
            C[(size_t)m * N + n] = acc[j4][reg];
        }
    }
}

// ---- causal depthwise conv (k=4) + silu: xz[:,:, :512] -> xc (f32 + bf16) --
// (un-fused from x_proj: the fused version was grid-starved at 64 blocks,
//  2.3% occupancy, 51 us — this elementwise form runs at 8192 blocks)
__global__ __launch_bounds__(256) void conv_silu_kernel(
    const float* __restrict__ xz, const float* __restrict__ cw,
    const float* __restrict__ cb, float* __restrict__ xc,
    unsigned short* __restrict__ xcb)
{
    int idx = blockIdx.x * 256 + threadIdx.x;   // B*L*DIN, d fastest
    int d = idx & (DIN - 1);
    int bl = idx >> 9;
    int l = bl & (L_ - 1);
    int b = bl >> 10;
    float acc = cb[d];
    #pragma unroll
    for (int k = 0; k < 4; ++k) {
        int ls = l - 3 + k;
        if (ls >= 0)
            acc = fmaf(xz[((size_t)(b * L_ + ls)) * (2 * DIN) + d], cw[d * 4 + k], acc);
    }
    float v = siluf(acc);
    xc[idx] = v;
    xcb[idx] = f2bf(v);
}

// ---- generic bf16 MFMA GEMM (x_proj, out_proj): C (+)= A @ W^T ----
__global__ __launch_bounds__(256) void gemm_bt_bf16(
    const unsigned short* __restrict__ A, const unsigned short* __restrict__ W,
    float* C, int M, int N, int K, int lda, int accumulate)
{
    __shared__ unsigned short As[64][72];
    __shared__ unsigned short Ws[64][72];
    const int tid = threadIdx.x;
    const int wave = tid >> 6;
    const int lane = tid & 63;
    const int m_l = lane & 15;
    const int q = lane >> 4;
    const int m0 = blockIdx.y * 64;
    const int n0 = blockIdx.x * 64;
    const int sr = tid >> 3;
    const int sc = (tid & 7) * 8;

    float4v acc[4];
    #pragma unroll
    for (int j = 0; j < 4; ++j) acc[j] = (float4v)(0.f);

    for (int k0 = 0; k0 < K; k0 += 64) {
        *(short8*)&As[sr][sc]      = *(const short8*)(A + (size_t)(m0 + sr) * lda + k0 + sc);
        *(short8*)&As[sr + 32][sc] = *(const short8*)(A + (size_t)(m0 + sr + 32) * lda + k0 + sc);
        short8 wz = (short8)0;
        int wn0 = n0 + sr, wn1 = n0 + sr + 32;
        *(short8*)&Ws[sr][sc]      = (wn0 < N) ? *(const short8*)(W + (size_t)wn0 * K + k0 + sc) : wz;
        *(short8*)&Ws[sr + 32][sc] = (wn1 < N) ? *(const short8*)(W + (size_t)wn1 * K + k0 + sc) : wz;
        __syncthreads();
        #pragma unroll
        for (int kk = 0; kk < 64; kk += 32) {
            short8 a = *(const short8*)&As[wave * 16 + m_l][kk + q * 8];
            #pragma unroll
            for (int j4 = 0; j4 < 4; ++j4) {
                short8 bf = *(const short8*)&Ws[j4 * 16 + m_l][kk + q * 8];
                acc[j4] = __builtin_amdgcn_mfma_f32_16x16x32_bf16(a, bf, acc[j4], 0, 0, 0);
            }
        }
        __syncthreads();
    }
    #pragma unroll
    for (int j4 = 0; j4 < 4; ++j4) {
        int n = n0 + j4 * 16 + m_l;
        if (n < N) {
            #pragma unroll
            for (int reg = 0; reg < 4; ++reg) {
                int m = m0 + wave * 16 + q * 4 + reg;
                float* cp = C + (size_t)m * N + n;
                if (accumulate) *cp += acc[j4][reg];
                else            *cp  = acc[j4][reg];
            }
        }
    }
}

// ==== chunked selective scan, thread-per-channel, fused delta recompute ====
__global__ __launch_bounds__(256) void scan_summary_kernel(
    const float* __restrict__ dbc, const float* __restrict__ xc,
    const float* __restrict__ A_log, const float* __restrict__ dt_w,
    const float* __restrict__ dt_b,
    float* __restrict__ S, float* __restrict__ H)
{
    const int d = blockIdx.x * 256 + threadIdx.x;
    const int c = blockIdx.y;
    const int b = blockIdx.z;
    float A[NST], tw[DTR];
    #pragma unroll
    for (int j = 0; j < NST; ++j) A[j] = -__expf(A_log[d * NST + j]);
    #pragma unroll
    for (int r = 0; r < DTR; ++r) tw[r] = dt_w[d * DTR + r];
    const float tb = dt_b[d];
    const int l0 = c * CT;
    const float* xp = xc  + ((size_t)(b * L_ + l0)) * DIN + d;
    const float* bc = dbc + ((size_t)(b * L_ + l0)) * 48;
    float h[NST];
    #pragma unroll
    for (int j = 0; j < NST; ++j) h[j] = 0.f;
    float ssum = 0.f;
    #pragma unroll 4
    for (int t = 0; t < CT; ++t) {
        const float* br = bc + t * 48;        // block-uniform row
        float acc = tb;
        #pragma unroll
        for (int r = 0; r < DTR; ++r) acc = fmaf(br[r], tw[r], acc);
        float dlt = softplusf(acc);
        float xcv = xp[t * DIN];
        float t0 = dlt * xcv;
        ssum += dlt;
        #pragma unroll
        for (int j = 0; j < NST; ++j) {
            float dA = __expf(A[j] * dlt);
            h[j] = fmaf(dA, h[j], t0 * br[DTR + j]);
        }
    }
    S[((size_t)b * CHK + c) * DIN + d] = ssum;
    float* Hp = H + (((size_t)b * CHK + c) * DIN + d) * NST;
    #pragma unroll
    for (int j = 0; j < NST; j += 4)
        *(float4*)(Hp + j) = make_float4(h[j], h[j + 1], h[j + 2], h[j + 3]);
}

// apply with fused prefix: prologue reconstructs h_in(c) from raw chunk
// summaries (S = per-chunk sum(delta), H = per-chunk local scan from 0).
__global__ __launch_bounds__(256) void scan_apply_kernel(
    const float* __restrict__ dbc, const float* __restrict__ xc,
    const float* __restrict__ xz, const float* __restrict__ A_log,
    const float* __restrict__ dt_w, const float* __restrict__ dt_b,
    const float* __restrict__ Dskip, const float* __restrict__ S,
    const float* __restrict__ H, unsigned short* __restrict__ y)
{
    const int d = blockIdx.x * 256 + threadIdx.x;
    const int c = blockIdx.y;
    const int b = blockIdx.z;
    float A[NST], tw[DTR];
    #pragma unroll
    for (int j = 0; j < NST; ++j) A[j] = -__expf(A_log[d * NST + j]);
    #pragma unroll
    for (int r = 0; r < DTR; ++r) tw[r] = dt_w[d * DTR + r];
    const float tb = dt_b[d];
    const float Dsk = Dskip[d];
    const int l0 = c * CT;
    const float* xp = xc  + ((size_t)(b * L_ + l0)) * DIN + d;
    const float* bc = dbc + ((size_t)(b * L_ + l0)) * 48;
    const float* zp = xz  + ((size_t)(b * L_ + l0)) * (2 * DIN) + DIN + d;
    unsigned short* yp = y + ((size_t)(b * L_ + l0)) * DIN + d;

    // prologue: h_in(c) = scan over chunk summaries 0..c-1
    float h[NST];
    #pragma unroll
    for (int j = 0; j < NST; ++j) h[j] = 0.f;
    {
        const float* Sp = S + (size_t)b * CHK * DIN + d;
        const float* Hp = H + ((size_t)b * CHK * DIN + d) * NST;
        for (int cc = 0; cc < c; ++cc) {
            float Sc = Sp[(size_t)cc * DIN];
            const float* Hc = Hp + (size_t)cc * DIN * NST;
            #pragma unroll
            for (int j = 0; j < NST; ++j)
                h[j] = fmaf(__expf(A[j] * Sc), h[j], Hc[j]);
        }
    }

    #pragma unroll 4
    for (int t = 0; t < CT; ++t) {
        const float* br = bc + t * 48;        // block-uniform row
        float acc = tb;
        #pragma unroll
        for (int r = 0; r < DTR; ++r) acc = fmaf(br[r], tw[r], acc);
        float dlt = softplusf(acc);
        float xcv = xp[t * DIN];
        float zv  = zp[t * (2 * DIN)];
        float t0 = dlt * xcv;
        float p = 0.f;
        #pragma unroll
        for (int j = 0; j < NST; ++j) {
            float dA = __expf(A[j] * dlt);
            h[j] = fmaf(dA, h[j], t0 * br[DTR + j]);
            p = fmaf(h[j], br[DTR + NST + j], p);
        }
        yp[t * DIN] = f2bf((p + xcv * Dsk) * siluf(zv));
    }
}

// ---- mean over L -> layernorm -> classifier; one block per batch ----
__global__ __launch_bounds__(256) void head_kernel(
    const float* __restrict__ h, const float* __restrict__ fn_w,
    const float* __restrict__ fn_b, const float* __restrict__ cls_w,
    const float* __restrict__ cls_b, float* __restrict__ out)
{
    int b = blockIdx.x, t = threadIdx.x;
    const float* hp = h + (size_t)b * L_ * DM + t;
    float s = 0.f;
    for (int l = 0; l < L_; ++l) s += hp[(size_t)l * DM];
    s *= (1.f / L_);
    float a = s, q = s * s;
    block_reduce2(a, q);
    float mu = a * (1.f / DM);
    float var = q * (1.f / DM) - mu * mu;
    float v = (s - mu) * rsqrtf(var + 1e-5f) * fn_w[t] + fn_b[t];
    __shared__ float pooled[DM];
    pooled[t] = v;
    __syncthreads();
    if (t < 10) {
        float acc = cls_b[t];
        for (int d2 = 0; d2 < DM; ++d2)
            acc = fmaf(pooled[d2], cls_w[t * DM + d2], acc);
        out[b * 10 + t] = acc;
    }
}

extern "C" void kernel_launch(void* const* d_in, const int* in_sizes, int n_in,
                              void* d_out, int out_size, void* d_ws, size_t ws_size,
                              hipStream_t stream)
{
    const float* x    = (const float*)d_in[0];
    const float* ipw  = (const float*)d_in[1];
    const float* ipb  = (const float*)d_in[2];
    const float* inw  = (const float*)d_in[3];
    const float* cw   = (const float*)d_in[4];
    const float* cb   = (const float*)d_in[5];
    const float* xpw  = (const float*)d_in[6];
    const float* dtw  = (const float*)d_in[7];
    const float* dtb  = (const float*)d_in[8];
    const float* alog = (const float*)d_in[9];
    const float* dsk  = (const float*)d_in[10];
    const float* opw  = (const float*)d_in[11];
    const float* lnw  = (const float*)d_in[12];
    const float* lnb  = (const float*)d_in[13];
    const float* fnw  = (const float*)d_in[14];
    const float* fnb  = (const float*)d_in[15];
    const float* clw  = (const float*)d_in[16];
    const float* clb  = (const float*)d_in[17];

    // workspace layout (float units)
    float* ws     = (float*)d_ws;
    float* hbuf   = ws;                                   // B*L*DM = 1,048,576 f
    float* xzbuf  = hbuf   + (size_t)B_ * L_ * DM;        // 4,194,304 f
    float* xcbuf  = xzbuf  + (size_t)B_ * L_ * 2 * DIN;   // 2,097,152 f
    float* dbcbuf = xcbuf  + (size_t)B_ * L_ * DIN;       //   196,608 f
    float* Sbuf   = dbcbuf + (size_t)B_ * L_ * 48;        //    65,536 f
    float* Hbuf   = Sbuf   + (size_t)B_ * CHK * DIN;      // 1,048,576 f
    float* tail   = Hbuf   + (size_t)B_ * CHK * DIN * NST;
    unsigned short* yb16  = (unsigned short*)tail;                  // B*L*DIN sh
    unsigned short* xcb16 = yb16  + (size_t)B_ * L_ * DIN;          // B*L*DIN sh
    unsigned short* inw16 = xcb16 + (size_t)B_ * L_ * DIN;// 4*1024*256
    unsigned short* xpw16 = inw16 + (size_t)4 * 1024 * DM;// 4*48*512
    unsigned short* opw16 = xpw16 + (size_t)4 * 48 * DIN; // 4*256*512

    const int BL = B_ * L_;                               // 4096
    const int NIN = 4 * 1024 * DM, NXP = 4 * 48 * DIN, NOP = 4 * DM * DIN;

    f2bf3_kernel<<<(NIN + NXP + NOP + 255) / 256, 256, 0, stream>>>(
        inw, NIN, xpw, NXP, opw, NOP, inw16, xpw16, opw16);

    input_proj_kernel<<<BL * DM / 256, 256, 0, stream>>>(x, ipw, ipb, hbuf);

    for (int i = 0; i < 4; ++i) {
        // xz = LN(h) @ in_w^T   [4096,1024], LN fused
        gemm_in_ln<<<dim3(2 * DIN / 64, BL / 64), 256, 0, stream>>>(
            hbuf, inw16 + (size_t)i * 1024 * DM, lnw + i * DM, lnb + i * DM,
            xzbuf, 2 * DIN);
        // xc = silu(conv(xz_lo))  (elementwise, full grid)
        conv_silu_kernel<<<BL * DIN / 256, 256, 0, stream>>>(
            xzbuf, cw + i * DIN * 4, cb + i * DIN, xcbuf, xcb16);
        // dbc = xc @ xp_w^T  [4096,48]
        gemm_bt_bf16<<<dim3(1, BL / 64), 256, 0, stream>>>(
            xcb16, xpw16 + (size_t)i * 48 * DIN, dbcbuf, BL, 48, DIN, DIN, 0);
        // chunked scan: summary -> apply (prefix fused into apply)
        scan_summary_kernel<<<dim3(DIN / 256, CHK, B_), 256, 0, stream>>>(
            dbcbuf, xcbuf, alog + i * DIN * NST, dtw + i * DIN * DTR,
            dtb + i * DIN, Sbuf, Hbuf);
        scan_apply_kernel<<<dim3(DIN / 256, CHK, B_), 256, 0, stream>>>(
            dbcbuf, xcbuf, xzbuf, alog + i * DIN * NST, dtw + i * DIN * DTR,
            dtb + i * DIN, dsk + i * DIN, Sbuf, Hbuf, yb16);
        // h += y @ out_w^T   [4096,256]
        gemm_bt_bf16<<<dim3(DM / 64, BL / 64), 256, 0, stream>>>(
            yb16, opw16 + (size_t)i * DM * DIN, hbuf, BL, DM, DIN, DIN, 1);
    }

    head_kernel<<<B_, 256, 0, stream>>>(hbuf, fnw, fnb, clw, clb, (float*)d_out);
}

// Round 8
// 492.298 us; speedup vs baseline: 1.5985x; 1.2715x over previous
//
#include <hip/hip_runtime.h>
#include <math.h>

#define B_ 4
#define L_ 1024
#define DM 256
#define DIN 512
#define NST 16
#define DTR 16
#define CHK 64          // number of chunks over L
#define CT (L_ / CHK)   // chunk length = 16

typedef short short8 __attribute__((ext_vector_type(8)));
typedef float float4v __attribute__((ext_vector_type(4)));

__device__ __forceinline__ float softplusf(float x) {
    return (x > 20.f) ? x : log1pf(__expf(x));
}
__device__ __forceinline__ float siluf(float x) {
    return x / (1.f + __expf(-x));
}
__device__ __forceinline__ unsigned short f2bf(float f) {  // RNE bf16
    unsigned int u = __float_as_uint(f);
    u = (u + 0x7fffu + ((u >> 16) & 1u)) >> 16;
    return (unsigned short)u;
}

// two-value block reduction (sum) over 256 threads = 4 waves
__device__ __forceinline__ void block_reduce2(float& a, float& q) {
    #pragma unroll
    for (int off = 32; off > 0; off >>= 1) {
        a += __shfl_down(a, off);
        q += __shfl_down(q, off);
    }
    __shared__ float sa[4], sq[4];
    int lane = threadIdx.x & 63, w = threadIdx.x >> 6;
    if (lane == 0) { sa[w] = a; sq[w] = q; }
    __syncthreads();
    a = sa[0] + sa[1] + sa[2] + sa[3];
    q = sq[0] + sq[1] + sq[2] + sq[3];
}

// ---- fp32 -> bf16 weight conversion, all three weights in one dispatch ----
__global__ __launch_bounds__(256) void f2bf3_kernel(
    const float* __restrict__ a, int na, const float* __restrict__ b, int nb,
    const float* __restrict__ c, int nc,
    unsigned short* __restrict__ oa, unsigned short* __restrict__ ob,
    unsigned short* __restrict__ oc)
{
    int i = blockIdx.x * 256 + threadIdx.x;
    if (i < na) { oa[i] = f2bf(a[i]); return; }
    int j = i - na;
    if (j < nb) { ob[j] = f2bf(b[j]); return; }
    int k = j - nb;
    if (k < nc) oc[k] = f2bf(c[k]);
}

// ---- input projection: h0[b,l,d] = bias[d] + sum_c x[b,c,l] * W[d,c] ----
__global__ __launch_bounds__(256) void input_proj_kernel(
    const float* __restrict__ x, const float* __restrict__ W,
    const float* __restrict__ bias, float* __restrict__ h0)
{
    int idx = blockIdx.x * 256 + threadIdx.x;     // B*L*DM, d fastest
    int d = idx & (DM - 1);
    int bl = idx >> 8;
    int l = bl & (L_ - 1);
    int b = bl >> 10;
    const float* xb = x + (size_t)b * 3 * L_;
    float acc = bias[d];
    acc = fmaf(xb[0 * L_ + l], W[d * 3 + 0], acc);
    acc = fmaf(xb[1 * L_ + l], W[d * 3 + 1], acc);
    acc = fmaf(xb[2 * L_ + l], W[d * 3 + 2], acc);
    h0[idx] = acc;
}

// ---- fused LN + in_proj GEMM: C[M,N] = LN(A)[M,256] @ W[N,256]^T ----
__global__ __launch_bounds__(256) void gemm_in_ln(
    const float* __restrict__ A, const unsigned short* __restrict__ W,
    const float* __restrict__ lw, const float* __restrict__ lb,
    float* __restrict__ C, int N)
{
    __shared__ unsigned short As[64][264];   // 64 rows x K=256 (+8 pad)
    __shared__ unsigned short Ws[64][72];
    const int tid = threadIdx.x;
    const int wave = tid >> 6;
    const int lane = tid & 63;
    const int m_l = lane & 15;
    const int q = lane >> 4;
    const int m0 = blockIdx.y * 64;
    const int n0 = blockIdx.x * 64;

    // ---- phase 1: layernorm rows m0..m0+63 into As (bf16), coalesced ----
    {
        const int rg = lane >> 4;          // row within wave's group of 4
        const int c4 = lane & 15;          // col quad index
        #pragma unroll
        for (int p = 0; p < 4; ++p) {
            int r = p * 16 + wave * 4 + rg;        // 0..63
            const float* ap = A + (size_t)(m0 + r) * DM;
            float4 v[4];
            float s = 0.f, qq = 0.f;
            #pragma unroll
            for (int i = 0; i < 4; ++i) {
                v[i] = *(const float4*)(ap + i * 64 + c4 * 4);
                s  += v[i].x + v[i].y + v[i].z + v[i].w;
                qq += v[i].x * v[i].x + v[i].y * v[i].y
                    + v[i].z * v[i].z + v[i].w * v[i].w;
            }
            s += __shfl_xor(s, 1); qq += __shfl_xor(qq, 1);
            s += __shfl_xor(s, 2); qq += __shfl_xor(qq, 2);
            s += __shfl_xor(s, 4); qq += __shfl_xor(qq, 4);
            s += __shfl_xor(s, 8); qq += __shfl_xor(qq, 8);
            float mu = s * (1.f / DM);
            float var = qq * (1.f / DM) - mu * mu;
            float rs = rsqrtf(var + 1e-5f);
            #pragma unroll
            for (int i = 0; i < 4; ++i) {
                int col = i * 64 + c4 * 4;
                float4 wv = *(const float4*)(lw + col);
                float4 bv = *(const float4*)(lb + col);
                unsigned short* dst = &As[r][col];
                dst[0] = f2bf((v[i].x - mu) * rs * wv.x + bv.x);
                dst[1] = f2bf((v[i].y - mu) * rs * wv.y + bv.y);
                dst[2] = f2bf((v[i].z - mu) * rs * wv.z + bv.z);
                dst[3] = f2bf((v[i].w - mu) * rs * wv.w + bv.w);
            }
        }
    }
    __syncthreads();

    // ---- phase 2: K-loop, stage W slices, MFMA ----
    const int sr = tid >> 3;          // 0..31 staging row
    const int sc = (tid & 7) * 8;     // staging col (shorts)
    float4v acc[4];
    #pragma unroll
    for (int j = 0; j < 4; ++j) acc[j] = (float4v)(0.f);

    for (int k0 = 0; k0 < DM; k0 += 64) {
        *(short8*)&Ws[sr][sc]      = *(const short8*)(W + (size_t)(n0 + sr) * DM + k0 + sc);
        *(short8*)&Ws[sr + 32][sc] = *(const short8*)(W + (size_t)(n0 + sr + 32) * DM + k0 + sc);
        __syncthreads();
        #pragma unroll
        for (int kk = 0; kk < 64; kk += 32) {
            short8 a = *(const short8*)&As[wave * 16 + m_l][k0 + kk + q * 8];
            #pragma unroll
            for (int j4 = 0; j4 < 4; ++j4) {
                short8 b = *(const short8*)&Ws[j4 * 16 + m_l][kk + q * 8];
                acc[j4] = __builtin_amdgcn_mfma_f32_16x16x32_bf16(a, b, acc[j4], 0, 0, 0);
            }
        }
        __syncthreads();
    }
    #pragma unroll
    for (int j4 = 0; j4 < 4; ++j4) {
        int n = n0 + j4 * 16 + m_l;
        #pragma unroll
        for (int reg = 0; reg < 4; ++reg) {
            int m = m0 + wave * 16 + q * 4 + reg;
            C[(size_t)m * N + n] = acc[j4][reg];
        }
    }
}

// ---- causal depthwise conv (k=4) + silu: xz[:,:, :512] -> xc (f32 + bf16) --
__global__ __launch_bounds__(256) void conv_silu_kernel(
    const float* __restrict__ xz, const float* __restrict__ cw,
    const float* __restrict__ cb, float* __restrict__ xc,
    unsigned short* __restrict__ xcb)
{
    int idx = blockIdx.x * 256 + threadIdx.x;   // B*L*DIN, d fastest
    int d = idx & (DIN - 1);
    int bl = idx >> 9;
    int l = bl & (L_ - 1);
    int b = bl >> 10;
    float acc = cb[d];
    #pragma unroll
    for (int k = 0; k < 4; ++k) {
        int ls = l - 3 + k;
        if (ls >= 0)
            acc = fmaf(xz[((size_t)(b * L_ + ls)) * (2 * DIN) + d], cw[d * 4 + k], acc);
    }
    float v = siluf(acc);
    xc[idx] = v;
    xcb[idx] = f2bf(v);
}

// ---- 32x32-tile bf16 MFMA GEMM (small-N / occupancy-bound GEMMs) ----
// 4 waves = 2x2 over the 32x32 tile; 9KB LDS -> many blocks/CU.
__global__ __launch_bounds__(256) void gemm_bt32_bf16(
    const unsigned short* __restrict__ A, const unsigned short* __restrict__ W,
    float* C, int M, int N, int K, int lda, int accumulate)
{
    __shared__ unsigned short As[32][72];
    __shared__ unsigned short Ws[32][72];
    const int tid = threadIdx.x;
    const int wave = tid >> 6;
    const int lane = tid & 63;
    const int m_l = lane & 15;
    const int q = lane >> 4;
    const int rw = (wave & 1) * 16;          // row-half
    const int cw2 = (wave >> 1) * 16;        // col-half
    const int m0 = blockIdx.y * 32;
    const int n0 = blockIdx.x * 32;
    const int sr = tid >> 3;                 // 0..31
    const int sc = (tid & 7) * 8;

    float4v acc = (float4v)(0.f);
    for (int k0 = 0; k0 < K; k0 += 64) {
        *(short8*)&As[sr][sc] = *(const short8*)(A + (size_t)(m0 + sr) * lda + k0 + sc);
        short8 wz = (short8)0;
        int wn = n0 + sr;
        *(short8*)&Ws[sr][sc] = (wn < N) ? *(const short8*)(W + (size_t)wn * K + k0 + sc) : wz;
        __syncthreads();
        #pragma unroll
        for (int kk = 0; kk < 64; kk += 32) {
            short8 a = *(const short8*)&As[rw + m_l][kk + q * 8];
            short8 bf = *(const short8*)&Ws[cw2 + m_l][kk + q * 8];
            acc = __builtin_amdgcn_mfma_f32_16x16x32_bf16(a, bf, acc, 0, 0, 0);
        }
        __syncthreads();
    }
    int n = n0 + cw2 + m_l;
    if (n < N) {
        #pragma unroll
        for (int reg = 0; reg < 4; ++reg) {
            int m = m0 + rw + q * 4 + reg;
            float* cp = C + (size_t)m * N + n;
            if (accumulate) *cp += acc[reg];
            else            *cp  = acc[reg];
        }
    }
}

// ==== chunked selective scan, thread-per-channel, H in (b,c,n,d) planes ====
// All H/S accesses coalesced (d = thread index, innermost).

__global__ __launch_bounds__(256) void scan_summary_kernel(
    const float* __restrict__ dbc, const float* __restrict__ xc,
    const float* __restrict__ A_log, const float* __restrict__ dt_w,
    const float* __restrict__ dt_b,
    float* __restrict__ S, float* __restrict__ H)
{
    const int d = blockIdx.x * 256 + threadIdx.x;
    const int c = blockIdx.y;
    const int b = blockIdx.z;
    float A[NST], tw[DTR];
    #pragma unroll
    for (int j = 0; j < NST; ++j) A[j] = -__expf(A_log[d * NST + j]);
    #pragma unroll
    for (int r = 0; r < DTR; ++r) tw[r] = dt_w[d * DTR + r];
    const float tb = dt_b[d];
    const int l0 = c * CT;
    const float* xp = xc  + ((size_t)(b * L_ + l0)) * DIN + d;
    const float* bc = dbc + ((size_t)(b * L_ + l0)) * 48;
    float h[NST];
    #pragma unroll
    for (int j = 0; j < NST; ++j) h[j] = 0.f;
    float ssum = 0.f;
    #pragma unroll 4
    for (int t = 0; t < CT; ++t) {
        const float* br = bc + t * 48;        // block-uniform row
        float acc = tb;
        #pragma unroll
        for (int r = 0; r < DTR; ++r) acc = fmaf(br[r], tw[r], acc);
        float dlt = softplusf(acc);
        float xcv = xp[t * DIN];
        float t0 = dlt * xcv;
        ssum += dlt;
        #pragma unroll
        for (int j = 0; j < NST; ++j) {
            float dA = __expf(A[j] * dlt);
            h[j] = fmaf(dA, h[j], t0 * br[DTR + j]);
        }
    }
    S[((size_t)b * CHK + c) * DIN + d] = ssum;
    float* Hp = H + (((size_t)b * CHK + c) * NST) * DIN + d;
    #pragma unroll
    for (int j = 0; j < NST; ++j)
        Hp[(size_t)j * DIN] = h[j];           // coalesced per j
}

// prefix over chunk summaries, in place: H[c] <- h_in(c). Thread = (b,n,d),
// d fastest -> all loads/stores coalesced.
__global__ __launch_bounds__(256) void scan_prefix_kernel(
    const float* __restrict__ S, float* __restrict__ H,
    const float* __restrict__ A_log)
{
    int idx = blockIdx.x * 256 + threadIdx.x;  // B*NST*DIN, d fastest
    int d = idx & (DIN - 1);
    int n = (idx >> 9) & (NST - 1);
    int b = idx >> 13;
    float A = -__expf(A_log[d * NST + n]);
    float hprev = 0.f;
    const float* Sp = S + (size_t)b * CHK * DIN + d;
    float* Hp = H + (((size_t)b * CHK) * NST + n) * DIN + d;
    for (int c = 0; c < CHK; ++c) {
        float Hc = Hp[(size_t)c * NST * DIN];
        float Sc = Sp[(size_t)c * DIN];
        Hp[(size_t)c * NST * DIN] = hprev;                  // h_in(c)
        hprev = fmaf(__expf(A * Sc), hprev, Hc);
    }
}

__global__ __launch_bounds__(256) void scan_apply_kernel(
    const float* __restrict__ dbc, const float* __restrict__ xc,
    const float* __restrict__ xz, const float* __restrict__ A_log,
    const float* __restrict__ dt_w, const float* __restrict__ dt_b,
    const float* __restrict__ Dskip, const float* __restrict__ H,
    unsigned short* __restrict__ y)
{
    const int d = blockIdx.x * 256 + threadIdx.x;
    const int c = blockIdx.y;
    const int b = blockIdx.z;
    float A[NST], tw[DTR];
    #pragma unroll
    for (int j = 0; j < NST; ++j) A[j] = -__expf(A_log[d * NST + j]);
    #pragma unroll
    for (int r = 0; r < DTR; ++r) tw[r] = dt_w[d * DTR + r];
    const float tb = dt_b[d];
    const float Dsk = Dskip[d];
    const int l0 = c * CT;
    const float* xp = xc  + ((size_t)(b * L_ + l0)) * DIN + d;
    const float* bc = dbc + ((size_t)(b * L_ + l0)) * 48;
    const float* zp = xz  + ((size_t)(b * L_ + l0)) * (2 * DIN) + DIN + d;
    unsigned short* yp = y + ((size_t)(b * L_ + l0)) * DIN + d;

    // h_in for this chunk (precomputed by prefix), coalesced loads
    float h[NST];
    const float* Hp = H + (((size_t)b * CHK + c) * NST) * DIN + d;
    #pragma unroll
    for (int j = 0; j < NST; ++j) h[j] = Hp[(size_t)j * DIN];

    #pragma unroll 4
    for (int t = 0; t < CT; ++t) {
        const float* br = bc + t * 48;        // block-uniform row
        float acc = tb;
        #pragma unroll
        for (int r = 0; r < DTR; ++r) acc = fmaf(br[r], tw[r], acc);
        float dlt = softplusf(acc);
        float xcv = xp[t * DIN];
        float zv  = zp[t * (2 * DIN)];
        float t0 = dlt * xcv;
        float p = 0.f;
        #pragma unroll
        for (int j = 0; j < NST; ++j) {
            float dA = __expf(A[j] * dlt);
            h[j] = fmaf(dA, h[j], t0 * br[DTR + j]);
            p = fmaf(h[j], br[DTR + NST + j], p);
        }
        yp[t * DIN] = f2bf((p + xcv * Dsk) * siluf(zv));
    }
}

// ---- mean over L -> layernorm -> classifier; one block per batch ----
__global__ __launch_bounds__(256) void head_kernel(
    const float* __restrict__ h, const float* __restrict__ fn_w,
    const float* __restrict__ fn_b, const float* __restrict__ cls_w,
    const float* __restrict__ cls_b, float* __restrict__ out)
{
    int b = blockIdx.x, t = threadIdx.x;
    const float* hp = h + (size_t)b * L_ * DM + t;
    float s = 0.f;
    for (int l = 0; l < L_; ++l) s += hp[(size_t)l * DM];
    s *= (1.f / L_);
    float a = s, q = s * s;
    block_reduce2(a, q);
    float mu = a * (1.f / DM);
    float var = q * (1.f / DM) - mu * mu;
    float v = (s - mu) * rsqrtf(var + 1e-5f) * fn_w[t] + fn_b[t];
    __shared__ float pooled[DM];
    pooled[t] = v;
    __syncthreads();
    if (t < 10) {
        float acc = cls_b[t];
        for (int d2 = 0; d2 < DM; ++d2)
            acc = fmaf(pooled[d2], cls_w[t * DM + d2], acc);
        out[b * 10 + t] = acc;
    }
}

extern "C" void kernel_launch(void* const* d_in, const int* in_sizes, int n_in,
                              void* d_out, int out_size, void* d_ws, size_t ws_size,
                              hipStream_t stream)
{
    const float* x    = (const float*)d_in[0];
    const float* ipw  = (const float*)d_in[1];
    const float* ipb  = (const float*)d_in[2];
    const float* inw  = (const float*)d_in[3];
    const float* cw   = (const float*)d_in[4];
    const float* cb   = (const float*)d_in[5];
    const float* xpw  = (const float*)d_in[6];
    const float* dtw  = (const float*)d_in[7];
    const float* dtb  = (const float*)d_in[8];
    const float* alog = (const float*)d_in[9];
    const float* dsk  = (const float*)d_in[10];
    const float* opw  = (const float*)d_in[11];
    const float* lnw  = (const float*)d_in[12];
    const float* lnb  = (const float*)d_in[13];
    const float* fnw  = (const float*)d_in[14];
    const float* fnb  = (const float*)d_in[15];
    const float* clw  = (const float*)d_in[16];
    const float* clb  = (const float*)d_in[17];

    // workspace layout (float units)
    float* ws     = (float*)d_ws;
    float* hbuf   = ws;                                   // B*L*DM = 1,048,576 f
    float* xzbuf  = hbuf   + (size_t)B_ * L_ * DM;        // 4,194,304 f
    float* xcbuf  = xzbuf  + (size_t)B_ * L_ * 2 * DIN;   // 2,097,152 f
    float* dbcbuf = xcbuf  + (size_t)B_ * L_ * DIN;       //   196,608 f
    float* Sbuf   = dbcbuf + (size_t)B_ * L_ * 48;        // B*CHK*DIN = 131,072 f
    float* Hbuf   = Sbuf   + (size_t)B_ * CHK * DIN;      // B*CHK*NST*DIN = 2,097,152 f
    float* tail   = Hbuf   + (size_t)B_ * CHK * NST * DIN;
    unsigned short* yb16  = (unsigned short*)tail;                  // B*L*DIN sh
    unsigned short* xcb16 = yb16  + (size_t)B_ * L_ * DIN;          // B*L*DIN sh
    unsigned short* inw16 = xcb16 + (size_t)B_ * L_ * DIN;// 4*1024*256
    unsigned short* xpw16 = inw16 + (size_t)4 * 1024 * DM;// 4*48*512
    unsigned short* opw16 = xpw16 + (size_t)4 * 48 * DIN; // 4*256*512

    const int BL = B_ * L_;                               // 4096
    const int NIN = 4 * 1024 * DM, NXP = 4 * 48 * DIN, NOP = 4 * DM * DIN;

    f2bf3_kernel<<<(NIN + NXP + NOP + 255) / 256, 256, 0, stream>>>(
        inw, NIN, xpw, NXP, opw, NOP, inw16, xpw16, opw16);

    input_proj_kernel<<<BL * DM / 256, 256, 0, stream>>>(x, ipw, ipb, hbuf);

    for (int i = 0; i < 4; ++i) {
        // xz = LN(h) @ in_w^T   [4096,1024], LN fused
        gemm_in_ln<<<dim3(2 * DIN / 64, BL / 64), 256, 0, stream>>>(
            hbuf, inw16 + (size_t)i * 1024 * DM, lnw + i * DM, lnb + i * DM,
            xzbuf, 2 * DIN);
        // xc = silu(conv(xz_lo))  (elementwise, full grid)
        conv_silu_kernel<<<BL * DIN / 256, 256, 0, stream>>>(
            xzbuf, cw + i * DIN * 4, cb + i * DIN, xcbuf, xcb16);
        // dbc = xc @ xp_w^T  [4096,48]  (32x32 tiles: 2x128 = 256 blocks)
        gemm_bt32_bf16<<<dim3(2, BL / 32), 256, 0, stream>>>(
            xcb16, xpw16 + (size_t)i * 48 * DIN, dbcbuf, BL, 48, DIN, DIN, 0);
        // chunked scan: summary -> prefix -> apply
        scan_summary_kernel<<<dim3(DIN / 256, CHK, B_), 256, 0, stream>>>(
            dbcbuf, xcbuf, alog + i * DIN * NST, dtw + i * DIN * DTR,
            dtb + i * DIN, Sbuf, Hbuf);
        scan_prefix_kernel<<<B_ * NST * DIN / 256, 256, 0, stream>>>(
            Sbuf, Hbuf, alog + i * DIN * NST);
        scan_apply_kernel<<<dim3(DIN / 256, CHK, B_), 256, 0, stream>>>(
            dbcbuf, xcbuf, xzbuf, alog + i * DIN * NST, dtw + i * DIN * DTR,
            dtb + i * DIN, dsk + i * DIN, Hbuf, yb16);
        // h += y @ out_w^T   [4096,256]  (32x32 tiles: 8x128 = 1024 blocks)
        gemm_bt32_bf16<<<dim3(DM / 32, BL / 32), 256, 0, stream>>>(
            yb16, opw16 + (size_t)i * DM * DIN, hbuf, BL, DM, DIN, DIN, 1);
    }

    head_kernel<<<B_, 256, 0, stream>>>(hbuf, fnw, fnb, clw, clb, (float*)d_out);
}

// Round 9
// 487.987 us; speedup vs baseline: 1.6127x; 1.0088x over previous
//
#include <hip/hip_runtime.h>
#include <math.h>

#define B_ 4
#define L_ 1024
#define DM 256
#define DIN 512
#define NST 16
#define DTR 16
#define CHK 64          // number of chunks over L
#define CT (L_ / CHK)   // chunk length = 16

typedef short short8 __attribute__((ext_vector_type(8)));
typedef float float4v __attribute__((ext_vector_type(4)));

__device__ __forceinline__ float softplusf(float x) {
    return (x > 20.f) ? x : log1pf(__expf(x));
}
__device__ __forceinline__ float siluf(float x) {
    return x / (1.f + __expf(-x));
}
__device__ __forceinline__ unsigned short f2bf(float f) {  // RNE bf16
    unsigned int u = __float_as_uint(f);
    u = (u + 0x7fffu + ((u >> 16) & 1u)) >> 16;
    return (unsigned short)u;
}

// two-value block reduction (sum) over 256 threads = 4 waves
__device__ __forceinline__ void block_reduce2(float& a, float& q) {
    #pragma unroll
    for (int off = 32; off > 0; off >>= 1) {
        a += __shfl_down(a, off);
        q += __shfl_down(q, off);
    }
    __shared__ float sa[4], sq[4];
    int lane = threadIdx.x & 63, w = threadIdx.x >> 6;
    if (lane == 0) { sa[w] = a; sq[w] = q; }
    __syncthreads();
    a = sa[0] + sa[1] + sa[2] + sa[3];
    q = sq[0] + sq[1] + sq[2] + sq[3];
}

// ---- prologue: weight f2bf conversions + input projection in ONE dispatch --
// blocks [0, nconv): convert inw/xpw/opw to bf16 (flat index)
// blocks [nconv, nconv+4096): h0[b,l,d] = ipb[d] + sum_c x[b,c,l]*ipw[d,c]
__global__ __launch_bounds__(256) void prologue_kernel(
    const float* __restrict__ inw, int na, const float* __restrict__ xpw, int nb,
    const float* __restrict__ opw, int nc,
    unsigned short* __restrict__ oa, unsigned short* __restrict__ ob,
    unsigned short* __restrict__ oc, int nconv,
    const float* __restrict__ x, const float* __restrict__ ipw,
    const float* __restrict__ ipb, float* __restrict__ h0)
{
    if ((int)blockIdx.x < nconv) {
        int i = blockIdx.x * 256 + threadIdx.x;
        if (i < na) { oa[i] = f2bf(inw[i]); return; }
        int j = i - na;
        if (j < nb) { ob[j] = f2bf(xpw[j]); return; }
        int k = j - nb;
        if (k < nc) oc[k] = f2bf(opw[k]);
        return;
    }
    int idx = (blockIdx.x - nconv) * 256 + threadIdx.x;   // B*L*DM, d fastest
    int d = idx & (DM - 1);
    int bl = idx >> 8;
    int l = bl & (L_ - 1);
    int b = bl >> 10;
    const float* xb = x + (size_t)b * 3 * L_;
    float acc = ipb[d];
    acc = fmaf(xb[0 * L_ + l], ipw[d * 3 + 0], acc);
    acc = fmaf(xb[1 * L_ + l], ipw[d * 3 + 1], acc);
    acc = fmaf(xb[2 * L_ + l], ipw[d * 3 + 2], acc);
    h0[idx] = acc;
}

// ---- fused LN + in_proj GEMM: C[M,N] = LN(A)[M,256] @ W[N,256]^T ----
__global__ __launch_bounds__(256) void gemm_in_ln(
    const float* __restrict__ A, const unsigned short* __restrict__ W,
    const float* __restrict__ lw, const float* __restrict__ lb,
    float* __restrict__ C, int N)
{
    __shared__ unsigned short As[64][264];   // 64 rows x K=256 (+8 pad)
    __shared__ unsigned short Ws[64][72];
    const int tid = threadIdx.x;
    const int wave = tid >> 6;
    const int lane = tid & 63;
    const int m_l = lane & 15;
    const int q = lane >> 4;
    const int m0 = blockIdx.y * 64;
    const int n0 = blockIdx.x * 64;

    // ---- phase 1: layernorm rows m0..m0+63 into As (bf16), coalesced ----
    {
        const int rg = lane >> 4;          // row within wave's group of 4
        const int c4 = lane & 15;          // col quad index
        #pragma unroll
        for (int p = 0; p < 4; ++p) {
            int r = p * 16 + wave * 4 + rg;        // 0..63
            const float* ap = A + (size_t)(m0 + r) * DM;
            float4 v[4];
            float s = 0.f, qq = 0.f;
            #pragma unroll
            for (int i = 0; i < 4; ++i) {
                v[i] = *(const float4*)(ap + i * 64 + c4 * 4);
                s  += v[i].x + v[i].y + v[i].z + v[i].w;
                qq += v[i].x * v[i].x + v[i].y * v[i].y
                    + v[i].z * v[i].z + v[i].w * v[i].w;
            }
            s += __shfl_xor(s, 1); qq += __shfl_xor(qq, 1);
            s += __shfl_xor(s, 2); qq += __shfl_xor(qq, 2);
            s += __shfl_xor(s, 4); qq += __shfl_xor(qq, 4);
            s += __shfl_xor(s, 8); qq += __shfl_xor(qq, 8);
            float mu = s * (1.f / DM);
            float var = qq * (1.f / DM) - mu * mu;
            float rs = rsqrtf(var + 1e-5f);
            #pragma unroll
            for (int i = 0; i < 4; ++i) {
                int col = i * 64 + c4 * 4;
                float4 wv = *(const float4*)(lw + col);
                float4 bv = *(const float4*)(lb + col);
                unsigned short* dst = &As[r][col];
                dst[0] = f2bf((v[i].x - mu) * rs * wv.x + bv.x);
                dst[1] = f2bf((v[i].y - mu) * rs * wv.y + bv.y);
                dst[2] = f2bf((v[i].z - mu) * rs * wv.z + bv.z);
                dst[3] = f2bf((v[i].w - mu) * rs * wv.w + bv.w);
            }
        }
    }
    __syncthreads();

    // ---- phase 2: K-loop, stage W slices, MFMA ----
    const int sr = tid >> 3;          // 0..31 staging row
    const int sc = (tid & 7) * 8;     // staging col (shorts)
    float4v acc[4];
    #pragma unroll
    for (int j = 0; j < 4; ++j) acc[j] = (float4v)(0.f);

    for (int k0 = 0; k0 < DM; k0 += 64) {
        *(short8*)&Ws[sr][sc]      = *(const short8*)(W + (size_t)(n0 + sr) * DM + k0 + sc);
        *(short8*)&Ws[sr + 32][sc] = *(const short8*)(W + (size_t)(n0 + sr + 32) * DM + k0 + sc);
        __syncthreads();
        #pragma unroll
        for (int kk = 0; kk < 64; kk += 32) {
            short8 a = *(const short8*)&As[wave * 16 + m_l][k0 + kk + q * 8];
            #pragma unroll
            for (int j4 = 0; j4 < 4; ++j4) {
                short8 b = *(const short8*)&Ws[j4 * 16 + m_l][kk + q * 8];
                acc[j4] = __builtin_amdgcn_mfma_f32_16x16x32_bf16(a, b, acc[j4], 0, 0, 0);
            }
        }
        __syncthreads();
    }
    #pragma unroll
    for (int j4 = 0; j4 < 4; ++j4) {
        int n = n0 + j4 * 16 + m_l;
        #pragma unroll
        for (int reg = 0; reg < 4; ++reg) {
            int m = m0 + wave * 16 + q * 4 + reg;
            C[(size_t)m * N + n] = acc[j4][reg];
        }
    }
}

// ---- causal depthwise conv (k=4) + silu: xz[:,:, :512] -> xc (f32 + bf16) --
__global__ __launch_bounds__(256) void conv_silu_kernel(
    const float* __restrict__ xz, const float* __restrict__ cw,
    const float* __restrict__ cb, float* __restrict__ xc,
    unsigned short* __restrict__ xcb)
{
    int idx = blockIdx.x * 256 + threadIdx.x;   // B*L*DIN, d fastest
    int d = idx & (DIN - 1);
    int bl = idx >> 9;
    int l = bl & (L_ - 1);
    int b = bl >> 10;
    float acc = cb[d];
    #pragma unroll
    for (int k = 0; k < 4; ++k) {
        int ls = l - 3 + k;
        if (ls >= 0)
            acc = fmaf(xz[((size_t)(b * L_ + ls)) * (2 * DIN) + d], cw[d * 4 + k], acc);
    }
    float v = siluf(acc);
    xc[idx] = v;
    xcb[idx] = f2bf(v);
}

// ---- 64x64-tile bf16 MFMA GEMM (out_proj; good MFMA:staging ratio) ----
__global__ __launch_bounds__(256) void gemm_bt_bf16(
    const unsigned short* __restrict__ A, const unsigned short* __restrict__ W,
    float* C, int M, int N, int K, int lda, int accumulate)
{
    __shared__ unsigned short As[64][72];
    __shared__ unsigned short Ws[64][72];
    const int tid = threadIdx.x;
    const int wave = tid >> 6;
    const int lane = tid & 63;
    const int m_l = lane & 15;
    const int q = lane >> 4;
    const int m0 = blockIdx.y * 64;
    const int n0 = blockIdx.x * 64;
    const int sr = tid >> 3;
    const int sc = (tid & 7) * 8;

    float4v acc[4];
    #pragma unroll
    for (int j = 0; j < 4; ++j) acc[j] = (float4v)(0.f);

    for (int k0 = 0; k0 < K; k0 += 64) {
        *(short8*)&As[sr][sc]      = *(const short8*)(A + (size_t)(m0 + sr) * lda + k0 + sc);
        *(short8*)&As[sr + 32][sc] = *(const short8*)(A + (size_t)(m0 + sr + 32) * lda + k0 + sc);
        short8 wz = (short8)0;
        int wn0 = n0 + sr, wn1 = n0 + sr + 32;
        *(short8*)&Ws[sr][sc]      = (wn0 < N) ? *(const short8*)(W + (size_t)wn0 * K + k0 + sc) : wz;
        *(short8*)&Ws[sr + 32][sc] = (wn1 < N) ? *(const short8*)(W + (size_t)wn1 * K + k0 + sc) : wz;
        __syncthreads();
        #pragma unroll
        for (int kk = 0; kk < 64; kk += 32) {
            short8 a = *(const short8*)&As[wave * 16 + m_l][kk + q * 8];
            #pragma unroll
            for (int j4 = 0; j4 < 4; ++j4) {
                short8 bf = *(const short8*)&Ws[j4 * 16 + m_l][kk + q * 8];
                acc[j4] = __builtin_amdgcn_mfma_f32_16x16x32_bf16(a, bf, acc[j4], 0, 0, 0);
            }
        }
        __syncthreads();
    }
    #pragma unroll
    for (int j4 = 0; j4 < 4; ++j4) {
        int n = n0 + j4 * 16 + m_l;
        if (n < N) {
            #pragma unroll
            for (int reg = 0; reg < 4; ++reg) {
                int m = m0 + wave * 16 + q * 4 + reg;
                float* cp = C + (size_t)m * N + n;
                if (accumulate) *cp += acc[j4][reg];
                else            *cp  = acc[j4][reg];
            }
        }
    }
}

// ---- 32x32-tile bf16 MFMA GEMM (x_proj: N=48 needs the finer grid) ----
__global__ __launch_bounds__(256) void gemm_bt32_bf16(
    const unsigned short* __restrict__ A, const unsigned short* __restrict__ W,
    float* C, int M, int N, int K, int lda, int accumulate)
{
    __shared__ unsigned short As[32][72];
    __shared__ unsigned short Ws[32][72];
    const int tid = threadIdx.x;
    const int wave = tid >> 6;
    const int lane = tid & 63;
    const int m_l = lane & 15;
    const int q = lane >> 4;
    const int rw = (wave & 1) * 16;          // row-half
    const int cw2 = (wave >> 1) * 16;        // col-half
    const int m0 = blockIdx.y * 32;
    const int n0 = blockIdx.x * 32;
    const int sr = tid >> 3;                 // 0..31
    const int sc = (tid & 7) * 8;

    float4v acc = (float4v)(0.f);
    for (int k0 = 0; k0 < K; k0 += 64) {
        *(short8*)&As[sr][sc] = *(const short8*)(A + (size_t)(m0 + sr) * lda + k0 + sc);
        short8 wz = (short8)0;
        int wn = n0 + sr;
        *(short8*)&Ws[sr][sc] = (wn < N) ? *(const short8*)(W + (size_t)wn * K + k0 + sc) : wz;
        __syncthreads();
        #pragma unroll
        for (int kk = 0; kk < 64; kk += 32) {
            short8 a = *(const short8*)&As[rw + m_l][kk + q * 8];
            short8 bf = *(const short8*)&Ws[cw2 + m_l][kk + q * 8];
            acc = __builtin_amdgcn_mfma_f32_16x16x32_bf16(a, bf, acc, 0, 0, 0);
        }
        __syncthreads();
    }
    int n = n0 + cw2 + m_l;
    if (n < N) {
        #pragma unroll
        for (int reg = 0; reg < 4; ++reg) {
            int m = m0 + rw + q * 4 + reg;
            float* cp = C + (size_t)m * N + n;
            if (accumulate) *cp += acc[reg];
            else            *cp  = acc[reg];
        }
    }
}

// ==== chunked selective scan, thread-per-channel, H in (b,c,n,d) planes ====

__global__ __launch_bounds__(256) void scan_summary_kernel(
    const float* __restrict__ dbc, const float* __restrict__ xc,
    const float* __restrict__ A_log, const float* __restrict__ dt_w,
    const float* __restrict__ dt_b,
    float* __restrict__ S, float* __restrict__ H)
{
    const int d = blockIdx.x * 256 + threadIdx.x;
    const int c = blockIdx.y;
    const int b = blockIdx.z;
    float A[NST], tw[DTR];
    #pragma unroll
    for (int j = 0; j < NST; ++j) A[j] = -__expf(A_log[d * NST + j]);
    #pragma unroll
    for (int r = 0; r < DTR; ++r) tw[r] = dt_w[d * DTR + r];
    const float tb = dt_b[d];
    const int l0 = c * CT;
    const float* xp = xc  + ((size_t)(b * L_ + l0)) * DIN + d;
    const float* bc = dbc + ((size_t)(b * L_ + l0)) * 48;
    float h[NST];
    #pragma unroll
    for (int j = 0; j < NST; ++j) h[j] = 0.f;
    float ssum = 0.f;
    #pragma unroll 4
    for (int t = 0; t < CT; ++t) {
        const float* br = bc + t * 48;        // block-uniform row
        float acc = tb;
        #pragma unroll
        for (int r = 0; r < DTR; ++r) acc = fmaf(br[r], tw[r], acc);
        float dlt = softplusf(acc);
        float xcv = xp[t * DIN];
        float t0 = dlt * xcv;
        ssum += dlt;
        #pragma unroll
        for (int j = 0; j < NST; ++j) {
            float dA = __expf(A[j] * dlt);
            h[j] = fmaf(dA, h[j], t0 * br[DTR + j]);
        }
    }
    S[((size_t)b * CHK + c) * DIN + d] = ssum;
    float* Hp = H + (((size_t)b * CHK + c) * NST) * DIN + d;
    #pragma unroll
    for (int j = 0; j < NST; ++j)
        Hp[(size_t)j * DIN] = h[j];           // coalesced per j
}

// prefix over chunk summaries, in place: H[c] <- h_in(c). Thread = (b,n,d),
// d fastest -> all loads/stores coalesced.
__global__ __launch_bounds__(256) void scan_prefix_kernel(
    const float* __restrict__ S, float* __restrict__ H,
    const float* __restrict__ A_log)
{
    int idx = blockIdx.x * 256 + threadIdx.x;  // B*NST*DIN, d fastest
    int d = idx & (DIN - 1);
    int n = (idx >> 9) & (NST - 1);
    int b = idx >> 13;
    float A = -__expf(A_log[d * NST + n]);
    float hprev = 0.f;
    const float* Sp = S + (size_t)b * CHK * DIN + d;
    float* Hp = H + (((size_t)b * CHK) * NST + n) * DIN + d;
    for (int c = 0; c < CHK; ++c) {
        float Hc = Hp[(size_t)c * NST * DIN];
        float Sc = Sp[(size_t)c * DIN];
        Hp[(size_t)c * NST * DIN] = hprev;                  // h_in(c)
        hprev = fmaf(__expf(A * Sc), hprev, Hc);
    }
}

__global__ __launch_bounds__(256) void scan_apply_kernel(
    const float* __restrict__ dbc, const float* __restrict__ xc,
    const float* __restrict__ xz, const float* __restrict__ A_log,
    const float* __restrict__ dt_w, const float* __restrict__ dt_b,
    const float* __restrict__ Dskip, const float* __restrict__ H,
    unsigned short* __restrict__ y)
{
    const int d = blockIdx.x * 256 + threadIdx.x;
    const int c = blockIdx.y;
    const int b = blockIdx.z;
    float A[NST], tw[DTR];
    #pragma unroll
    for (int j = 0; j < NST; ++j) A[j] = -__expf(A_log[d * NST + j]);
    #pragma unroll
    for (int r = 0; r < DTR; ++r) tw[r] = dt_w[d * DTR + r];
    const float tb = dt_b[d];
    const float Dsk = Dskip[d];
    const int l0 = c * CT;
    const float* xp = xc  + ((size_t)(b * L_ + l0)) * DIN + d;
    const float* bc = dbc + ((size_t)(b * L_ + l0)) * 48;
    const float* zp = xz  + ((size_t)(b * L_ + l0)) * (2 * DIN) + DIN + d;
    unsigned short* yp = y + ((size_t)(b * L_ + l0)) * DIN + d;

    // h_in for this chunk (precomputed by prefix), coalesced loads
    float h[NST];
    const float* Hp = H + (((size_t)b * CHK + c) * NST) * DIN + d;
    #pragma unroll
    for (int j = 0; j < NST; ++j) h[j] = Hp[(size_t)j * DIN];

    #pragma unroll 4
    for (int t = 0; t < CT; ++t) {
        const float* br = bc + t * 48;        // block-uniform row
        float acc = tb;
        #pragma unroll
        for (int r = 0; r < DTR; ++r) acc = fmaf(br[r], tw[r], acc);
        float dlt = softplusf(acc);
        float xcv = xp[t * DIN];
        float zv  = zp[t * (2 * DIN)];
        float t0 = dlt * xcv;
        float p = 0.f;
        #pragma unroll
        for (int j = 0; j < NST; ++j) {
            float dA = __expf(A[j] * dlt);
            h[j] = fmaf(dA, h[j], t0 * br[DTR + j]);
            p = fmaf(h[j], br[DTR + NST + j], p);
        }
        yp[t * DIN] = f2bf((p + xcv * Dsk) * siluf(zv));
    }
}

// ---- head, 2-stage (old single-stage ran on 4 blocks = 1.5% of GPU) ----
// stage 1: 64 blocks, each sums 64 L-rows of its batch -> partial[64][DM]
__global__ __launch_bounds__(256) void head_partial_kernel(
    const float* __restrict__ h, float* __restrict__ partial)
{
    int b = blockIdx.x >> 4, ch = blockIdx.x & 15, t = threadIdx.x;
    const float* hp = h + ((size_t)(b * L_ + ch * 64)) * DM + t;
    float s = 0.f;
    #pragma unroll 8
    for (int l = 0; l < 64; ++l) s += hp[(size_t)l * DM];
    partial[(size_t)blockIdx.x * DM + t] = s;
}

// stage 2: 4 blocks; reduce 16 partials -> mean -> LN -> classifier
__global__ __launch_bounds__(256) void head_final_kernel(
    const float* __restrict__ partial, const float* __restrict__ fn_w,
    const float* __restrict__ fn_b, const float* __restrict__ cls_w,
    const float* __restrict__ cls_b, float* __restrict__ out)
{
    int b = blockIdx.x, t = threadIdx.x;
    const float* pp = partial + (size_t)b * 16 * DM + t;
    float s = 0.f;
    #pragma unroll
    for (int c = 0; c < 16; ++c) s += pp[(size_t)c * DM];
    s *= (1.f / L_);
    float a = s, q = s * s;
    block_reduce2(a, q);
    float mu = a * (1.f / DM);
    float var = q * (1.f / DM) - mu * mu;
    float v = (s - mu) * rsqrtf(var + 1e-5f) * fn_w[t] + fn_b[t];
    __shared__ float pooled[DM];
    pooled[t] = v;
    __syncthreads();
    if (t < 10) {
        float acc = cls_b[t];
        for (int d2 = 0; d2 < DM; ++d2)
            acc = fmaf(pooled[d2], cls_w[t * DM + d2], acc);
        out[b * 10 + t] = acc;
    }
}

extern "C" void kernel_launch(void* const* d_in, const int* in_sizes, int n_in,
                              void* d_out, int out_size, void* d_ws, size_t ws_size,
                              hipStream_t stream)
{
    const float* x    = (const float*)d_in[0];
    const float* ipw  = (const float*)d_in[1];
    const float* ipb  = (const float*)d_in[2];
    const float* inw  = (const float*)d_in[3];
    const float* cw   = (const float*)d_in[4];
    const float* cb   = (const float*)d_in[5];
    const float* xpw  = (const float*)d_in[6];
    const float* dtw  = (const float*)d_in[7];
    const float* dtb  = (const float*)d_in[8];
    const float* alog = (const float*)d_in[9];
    const float* dsk  = (const float*)d_in[10];
    const float* opw  = (const float*)d_in[11];
    const float* lnw  = (const float*)d_in[12];
    const float* lnb  = (const float*)d_in[13];
    const float* fnw  = (const float*)d_in[14];
    const float* fnb  = (const float*)d_in[15];
    const float* clw  = (const float*)d_in[16];
    const float* clb  = (const float*)d_in[17];

    // workspace layout (float units)
    float* ws     = (float*)d_ws;
    float* hbuf   = ws;                                   // B*L*DM = 1,048,576 f
    float* xzbuf  = hbuf   + (size_t)B_ * L_ * DM;        // 4,194,304 f
    float* xcbuf  = xzbuf  + (size_t)B_ * L_ * 2 * DIN;   // 2,097,152 f
    float* dbcbuf = xcbuf  + (size_t)B_ * L_ * DIN;       //   196,608 f
    float* Sbuf   = dbcbuf + (size_t)B_ * L_ * 48;        // B*CHK*DIN = 131,072 f
    float* Hbuf   = Sbuf   + (size_t)B_ * CHK * DIN;      // B*CHK*NST*DIN = 2,097,152 f
    float* tail   = Hbuf   + (size_t)B_ * CHK * NST * DIN;
    unsigned short* yb16  = (unsigned short*)tail;                  // B*L*DIN sh
    unsigned short* xcb16 = yb16  + (size_t)B_ * L_ * DIN;          // B*L*DIN sh
    unsigned short* inw16 = xcb16 + (size_t)B_ * L_ * DIN;// 4*1024*256
    unsigned short* xpw16 = inw16 + (size_t)4 * 1024 * DM;// 4*48*512
    unsigned short* opw16 = xpw16 + (size_t)4 * 48 * DIN; // 4*256*512
    float* partial = (float*)(opw16 + (size_t)4 * DM * DIN);   // 64*DM f

    const int BL = B_ * L_;                               // 4096
    const int NIN = 4 * 1024 * DM, NXP = 4 * 48 * DIN, NOP = 4 * DM * DIN;
    const int NCONV = (NIN + NXP + NOP + 255) / 256;      // 6528 blocks

    prologue_kernel<<<NCONV + BL * DM / 256, 256, 0, stream>>>(
        inw, NIN, xpw, NXP, opw, NOP, inw16, xpw16, opw16, NCONV,
        x, ipw, ipb, hbuf);

    for (int i = 0; i < 4; ++i) {
        // xz = LN(h) @ in_w^T   [4096,1024], LN fused
        gemm_in_ln<<<dim3(2 * DIN / 64, BL / 64), 256, 0, stream>>>(
            hbuf, inw16 + (size_t)i * 1024 * DM, lnw + i * DM, lnb + i * DM,
            xzbuf, 2 * DIN);
        // xc = silu(conv(xz_lo))  (elementwise, full grid)
        conv_silu_kernel<<<BL * DIN / 256, 256, 0, stream>>>(
            xzbuf, cw + i * DIN * 4, cb + i * DIN, xcbuf, xcb16);
        // dbc = xc @ xp_w^T  [4096,48]  (32x32 tiles: 2x128 = 256 blocks)
        gemm_bt32_bf16<<<dim3(2, BL / 32), 256, 0, stream>>>(
            xcb16, xpw16 + (size_t)i * 48 * DIN, dbcbuf, BL, 48, DIN, DIN, 0);
        // chunked scan: summary -> prefix -> apply
        scan_summary_kernel<<<dim3(DIN / 256, CHK, B_), 256, 0, stream>>>(
            dbcbuf, xcbuf, alog + i * DIN * NST, dtw + i * DIN * DTR,
            dtb + i * DIN, Sbuf, Hbuf);
        scan_prefix_kernel<<<B_ * NST * DIN / 256, 256, 0, stream>>>(
            Sbuf, Hbuf, alog + i * DIN * NST);
        scan_apply_kernel<<<dim3(DIN / 256, CHK, B_), 256, 0, stream>>>(
            dbcbuf, xcbuf, xzbuf, alog + i * DIN * NST, dtw + i * DIN * DTR,
            dtb + i * DIN, dsk + i * DIN, Hbuf, yb16);
        // h += y @ out_w^T   [4096,256]  (64x64 tiles: 4x64 = 256 blocks)
        gemm_bt_bf16<<<dim3(DM / 64, BL / 64), 256, 0, stream>>>(
            yb16, opw16 + (size_t)i * DM * DIN, hbuf, BL, DM, DIN, DIN, 1);
    }

    head_partial_kernel<<<B_ * 16, 256, 0, stream>>>(hbuf, partial);
    head_final_kernel<<<B_, 256, 0, stream>>>(partial, fnw, fnb, clw, clb,
                                              (float*)d_out);
}